// Round 1
// baseline (2706.910 us; speedup 1.0000x reference)
//
#include <hip/hip_runtime.h>
#include <stdint.h>

#define N_PTS   65536
#define N_GRP   1024
#define K_NB    32
#define F_DIM   64

#define FPS_BLOCKS  16
#define FPS_THREADS 512
#define FPS_TT (FPS_BLOCKS*FPS_THREADS)   // 8192 threads
#define FPS_P  (N_PTS / FPS_TT)           // 8 points per thread

// ---------- helpers ----------
__device__ __forceinline__ unsigned long long packMaxKey(float v, unsigned int idx) {
  // distances are >= 0 -> raw float bits are monotonic; ties -> smaller idx wins under max
  return ((unsigned long long)__float_as_uint(v) << 32) | (0xFFFFFFFFu - idx);
}
__device__ __forceinline__ unsigned long long packMinKey(float v, unsigned int idx) {
  unsigned int b = __float_as_uint(v);
  b = (b & 0x80000000u) ? ~b : (b | 0x80000000u);   // total order flip (handles tiny negatives)
  return ((unsigned long long)b << 32) | idx;        // min => (value asc, idx asc)
}
__device__ __forceinline__ float unpackMinVal(unsigned long long k) {
  unsigned int b = (unsigned int)(k >> 32);
  b = (b & 0x80000000u) ? (b & 0x7FFFFFFFu) : ~b;
  return __uint_as_float(b);
}

// ---------- Phase 1: farthest point sampling (1023 sequential argmax rounds) ----------
__global__ void __launch_bounds__(FPS_THREADS)
fps_kernel(const float* __restrict__ x, unsigned long long* __restrict__ slots,
           unsigned int* __restrict__ cnts, float* __restrict__ centers)
{
  const int t = blockIdx.x * FPS_THREADS + threadIdx.x;
  float px[FPS_P], py[FPS_P], pz[FPS_P], d[FPS_P];
#pragma unroll
  for (int k = 0; k < FPS_P; ++k) {
    int p = t + k * FPS_TT;
    px[k] = x[p*3+0]; py[k] = x[p*3+1]; pz[k] = x[p*3+2];
    d[k] = 1e10f;                                  // matches INIT_DIST
  }
  float cx = x[0], cy = x[1], cz = x[2];           // first centroid = point 0
  if (blockIdx.x == 0 && threadIdx.x == 0) {
    centers[0] = cx; centers[1] = cy; centers[2] = cz;
  }
  __shared__ unsigned long long red[FPS_THREADS/64];

  for (int r = 1; r < N_GRP; ++r) {
    unsigned long long best = 0ull;
#pragma unroll
    for (int k = 0; k < FPS_P; ++k) {
      float e0 = px[k]-cx, e1 = py[k]-cy, e2 = pz[k]-cz;
      float dist = fmaf(e2,e2, fmaf(e1,e1, e0*e0));  // fma-contracted like XLA
      float dn = fminf(d[k], dist);
      d[k] = dn;
      unsigned long long pk = packMaxKey(dn, (unsigned)(t + k*FPS_TT));
      if (pk > best) best = pk;
    }
#pragma unroll
    for (int off = 32; off; off >>= 1) {
      unsigned long long o = __shfl_down(best, off);
      if (o > best) best = o;
    }
    const int wid = threadIdx.x >> 6;
    if ((threadIdx.x & 63) == 0) red[wid] = best;
    __syncthreads();
    if (threadIdx.x == 0) {
#pragma unroll
      for (int w = 1; w < FPS_THREADS/64; ++w) if (red[w] > best) best = red[w];
      atomicMax(&slots[r], best);
      __hip_atomic_fetch_add(&cnts[r], 1u, __ATOMIC_RELEASE, __HIP_MEMORY_SCOPE_AGENT);
      while (__hip_atomic_load(&cnts[r], __ATOMIC_ACQUIRE, __HIP_MEMORY_SCOPE_AGENT) < FPS_BLOCKS)
        __builtin_amdgcn_s_sleep(1);
      red[0] = __hip_atomic_load(&slots[r], __ATOMIC_RELAXED, __HIP_MEMORY_SCOPE_AGENT);
    }
    __syncthreads();
    const unsigned long long win = red[0];
    const int widx = (int)(0xFFFFFFFFu - (unsigned int)(win & 0xFFFFFFFFull));
    cx = x[widx*3+0]; cy = x[widx*3+1]; cz = x[widx*3+2];   // broadcast load, L2-hot
    if (blockIdx.x == 0 && threadIdx.x == 0) {
      centers[r*3+0] = cx; centers[r*3+1] = cy; centers[r*3+2] = cz;
    }
    __syncthreads();   // protect red[] reuse next round
  }
}

// ---------- Phase 2: per-group exact 32 smallest (sorted by value, then index) ----------
#define TKT 256
#define CAP 3072

__global__ void __launch_bounds__(TKT)
topk_kernel(const float* __restrict__ x, const float* __restrict__ feat,
            const float* __restrict__ centers, float* __restrict__ out)
{
  __shared__ float cv[CAP];
  __shared__ int   ci[CAP];
  __shared__ int   s_cnt;
  __shared__ float s_thr;
  __shared__ float selv[K_NB];
  __shared__ int   seli[K_NB];

  const int g = blockIdx.x, tid = threadIdx.x;
  const float cx = centers[g*3+0], cy = centers[g*3+1], cz = centers[g*3+2];
  const float c2 = fmaf(cz,cz, fmaf(cy,cy, cx*cx));
  if (tid == 0) { s_cnt = 0; s_thr = __builtin_inff(); }
  __syncthreads();

  const int CH = N_PTS / (TKT*8);   // 32 chunks
  for (int chunk = 0; chunk < CH; ++chunk) {
    const float lthr = s_thr;
#pragma unroll
    for (int k = 0; k < 8; ++k) {
      int p = (chunk*8 + k)*TKT + tid;
      float q0 = x[p*3+0], q1 = x[p*3+1], q2 = x[p*3+2];
      float dot  = fmaf(cz,q2, fmaf(cy,q1, cx*q0));
      float pp   = fmaf(q2,q2, fmaf(q1,q1, q0*q0));
      float dist = fmaf(-2.0f, dot, c2) + pp;   // ((-2*dot)+|c|^2)+|p|^2, -2*dot exact
      if (dist <= lthr) {
        int pos = atomicAdd(&s_cnt, 1);
        cv[pos] = dist; ci[pos] = p;
      }
    }
    __syncthreads();
    const int n = s_cnt;
    const bool last = (chunk == CH-1);
    if (n > (CAP - TKT*8) || last) {
      if (tid < 64) {   // single-wave exact K-extraction, deterministic (val,idx) order
        for (int it = 0; it < K_NB; ++it) {
          unsigned long long lk = ~0ull;
          for (int j = tid; j < n; j += 64) {
            unsigned long long kk = packMinKey(cv[j], (unsigned)ci[j]);
            if (kk < lk) lk = kk;
          }
#pragma unroll
          for (int off = 32; off; off >>= 1) {
            unsigned long long o = __shfl_xor(lk, off);
            if (o < lk) lk = o;
          }
          const int mi = (int)(unsigned int)(lk & 0xFFFFFFFFull);
          for (int j = tid; j < n; j += 64)
            if (ci[j] == mi) cv[j] = __builtin_inff();   // remove winner
          if (tid == 0) { selv[it] = unpackMinVal(lk); seli[it] = mi; }
        }
      }
      __syncthreads();
      if (!last) {      // compact buffer to current best-32, tighten threshold
        if (tid < K_NB) { cv[tid] = selv[tid]; ci[tid] = seli[tid]; }
        if (tid == 0)   { s_cnt = K_NB; s_thr = selv[K_NB-1]; }
        __syncthreads();
      }
    }
  }

  // gather neighbor features: out[g][j][c] = feat[seli[j]][c]
  const long base = (long)g * (K_NB*F_DIM);
#pragma unroll
  for (int m = 0; m < (K_NB*F_DIM)/TKT; ++m) {   // 8 iterations
    int lin = m*TKT + tid;
    int j = lin >> 6, c = lin & 63;
    out[base + lin] = feat[(long)seli[j]*F_DIM + c];
  }
}

// ---------- Phase 3: per-point argmin over 1024 centers ----------
__global__ void __launch_bounds__(256)
argmin_kernel(const float* __restrict__ x, const float* __restrict__ centers,
              float* __restrict__ outIdx)
{
  __shared__ float scx[N_GRP], scy[N_GRP], scz[N_GRP], sc2[N_GRP];
  for (int i = threadIdx.x; i < N_GRP; i += 256) {
    float a = centers[i*3+0], b = centers[i*3+1], c = centers[i*3+2];
    scx[i]=a; scy[i]=b; scz[i]=c;
    sc2[i] = fmaf(c,c, fmaf(b,b, a*a));
  }
  __syncthreads();
  const int p = blockIdx.x*256 + threadIdx.x;
  const float q0 = x[p*3+0], q1 = x[p*3+1], q2 = x[p*3+2];
  const float pp = fmaf(q2,q2, fmaf(q1,q1, q0*q0));
  float best = __builtin_inff(); int bi = 0;
#pragma unroll 4
  for (int c = 0; c < N_GRP; ++c) {
    float dot  = fmaf(scz[c],q2, fmaf(scy[c],q1, scx[c]*q0));
    float dist = fmaf(-2.0f, dot, sc2[c]) + pp;
    if (dist < best) { best = dist; bi = c; }   // strict < keeps FIRST min (jnp.argmin)
  }
  outIdx[p] = (float)bi;
}

// ---------- launch ----------
extern "C" void kernel_launch(void* const* d_in, const int* in_sizes, int n_in,
                              void* d_out, int out_size, void* d_ws, size_t ws_size,
                              hipStream_t stream)
{
  const float* x    = (const float*)d_in[0];
  const float* feat = (const float*)d_in[1];
  float* out = (float*)d_out;
  char* ws = (char*)d_ws;
  unsigned long long* slots = (unsigned long long*)ws;   // 8 KiB  (1024 u64)
  unsigned int*       cnts  = (unsigned int*)(ws + 8192);// 4 KiB  (1024 u32)
  float*              ctr   = (float*)(ws + 12288);      // 12 KiB (1024*3 f32)

  // per-call re-init of barrier counters + argmax slots (graph-replay safe)
  hipMemsetAsync(ws, 0, 12288, stream);

  const float* xArg = x;
  unsigned long long* sArg = slots;
  unsigned int* cArg = cnts;
  float* ctrArg = ctr;
  void* kargs[] = { (void*)&xArg, (void*)&sArg, (void*)&cArg, (void*)&ctrArg };
  if (hipLaunchCooperativeKernel(fps_kernel, dim3(FPS_BLOCKS), dim3(FPS_THREADS),
                                 kargs, 0u, stream) != hipSuccess) {
    // fallback: plain launch (16 blocks trivially co-resident on 256 CUs)
    hipLaunchKernelGGL(fps_kernel, dim3(FPS_BLOCKS), dim3(FPS_THREADS), 0, stream,
                       x, slots, cnts, ctr);
  }
  hipLaunchKernelGGL(topk_kernel, dim3(N_GRP), dim3(TKT), 0, stream, x, feat, ctr, out);
  hipLaunchKernelGGL(argmin_kernel, dim3(N_PTS/256), dim3(256), 0, stream,
                     x, ctr, out + (size_t)N_GRP*K_NB*F_DIM);
}